// Round 3
// baseline (3350.467 us; speedup 1.0000x reference)
//
#include <hip/hip_runtime.h>

#define NFC   256
#define DIMD  1024
#define NN    12
#define BTB   64
#define S_TOT 3600
#define BN    768        // BT*N
#define EMB_K 6400       // NFC*5*5
#define IMG_C 768
#define LN_EPS 1e-5f
#define SCH   360        // s-chunk per block (10 chunks)
#define NCH   10
#define SUB   120        // online sub-tile: live set 512*768*120*4 = 188MB < L3
#define NSUB  3          // 3*120 = 360

// ---------------- reduction helpers (block = 256 threads = 4 waves) ----------
__device__ __forceinline__ float waveSum(float v) {
#pragma unroll
  for (int off = 32; off > 0; off >>= 1) v += __shfl_down(v, off, 64);
  return v;
}
__device__ __forceinline__ float blockSum256(float v, float* sm) {
  v = waveSum(v);
  __syncthreads();
  if ((threadIdx.x & 63) == 0) sm[threadIdx.x >> 6] = v;
  __syncthreads();
  return sm[0] + sm[1] + sm[2] + sm[3];
}

// ---------------- K0: tiled weight transposes [256][Cin] -> [Cin][256] -------
// 64x64 LDS tiles, coalesced both sides (old version did 64-way strided reads).
__global__ __launch_bounds__(256) void k_transpose_all(
    const float* __restrict__ w_ds1, const float* __restrict__ w_emb,
    const float* __restrict__ w_ds2, const float* __restrict__ f1,
    const float* __restrict__ f2,
    float* __restrict__ w1T, float* __restrict__ wembT,
    float* __restrict__ wds2T, float* __restrict__ w1Tf,
    float* __restrict__ w2Tf) {
  __shared__ float tile[64][65];
  const int blk = blockIdx.x;
  const float* in; float* out; int Cin; int rel;
  if (blk < 64)       { in = w_ds1; out = w1T;   Cin = 1024; rel = blk; }
  else if (blk < 464) { in = w_emb; out = wembT; Cin = 6400; rel = blk - 64; }
  else if (blk < 512) { in = w_ds2; out = wds2T; Cin = 768;  rel = blk - 464; }
  else if (blk < 528) { in = f1;    out = w1Tf;  Cin = 256;  rel = blk - 512; }
  else                { in = f2;    out = w2Tf;  Cin = 256;  rel = blk - 528; }
  const int jt = Cin >> 6;
  const int i0 = (rel / jt) << 6;     // row tile within 256
  const int j0 = (rel % jt) << 6;     // col tile within Cin
  const int tx = threadIdx.x & 63, ty = threadIdx.x >> 6;
#pragma unroll
  for (int k = 0; k < 16; ++k) {
    const int i = ty + k * 4;
    tile[i][tx] = in[(size_t)(i0 + i) * Cin + j0 + tx];   // coalesced read
  }
  __syncthreads();
#pragma unroll
  for (int k = 0; k < 16; ++k) {
    const int j = ty + k * 4;
    out[(size_t)(j0 + j) * 256 + i0 + tx] = tile[tx][j];  // coalesced write
  }
}

// ---------------- K1: ROI downsample1 ----------------------------------------
__global__ __launch_bounds__(256) void k_ds1(const float* __restrict__ RF,   // [BN][1024][25]
                                             const float* __restrict__ w1T,  // [1024][256]
                                             const float* __restrict__ b1,
                                             float* __restrict__ roi_ds) {   // [BN][6400]
  const int r = blockIdx.x;
  const int c = threadIdx.x;
  const float* __restrict__ rf = RF + (size_t)r * (DIMD * 25);
  float acc[25];
#pragma unroll
  for (int p = 0; p < 25; ++p) acc[p] = 0.f;
#pragma unroll 2
  for (int d = 0; d < DIMD; ++d) {
    const float w = w1T[(size_t)d * NFC + c];        // coalesced
#pragma unroll
    for (int p = 0; p < 25; ++p)
      acc[p] = fmaf(w, rf[d * 25 + p], acc[p]);      // uniform -> scalar loads
  }
  const float bias = b1[c];
  float* out = roi_ds + (size_t)r * EMB_K + c * 25;
#pragma unroll
  for (int p = 0; p < 25; ++p) out[p] = acc[p] + bias;
}

// ---------------- K2: emb partial GEMM, k-split 8 ----------------------------
__global__ __launch_bounds__(256) void k_emb_part(const float* __restrict__ roi_ds,
                                                  const float* __restrict__ wembT,
                                                  float* __restrict__ emb_part) { // [8][BN][256]
  const int r0 = blockIdx.x * 16;
  const int kz = blockIdx.y;
  const int c = threadIdx.x;
  const int k0 = kz * (EMB_K / 8);
  float acc[16];
#pragma unroll
  for (int r = 0; r < 16; ++r) acc[r] = 0.f;
#pragma unroll 4
  for (int k = k0; k < k0 + EMB_K / 8; ++k) {
    const float w = wembT[(size_t)k * NFC + c];
#pragma unroll
    for (int r = 0; r < 16; ++r)
      acc[r] = fmaf(w, roi_ds[(size_t)(r0 + r) * EMB_K + k], acc[r]);
  }
#pragma unroll
  for (int r = 0; r < 16; ++r)
    emb_part[((size_t)kz * BN + r0 + r) * NFC + c] = acc[r];
}

__global__ __launch_bounds__(256) void k_emb_reduce(const float* __restrict__ emb_part,
                                                    const float* __restrict__ bemb,
                                                    float* __restrict__ emb) {
  int i = blockIdx.x * 256 + threadIdx.x;
  float s = bemb[i & 255];
#pragma unroll
  for (int z = 0; z < 8; ++z) s += emb_part[(size_t)z * BN * NFC + i];
  emb[i] = s;
}

// ---------------- K3: e2T = (emb @ w_ds2) transposed to [64][768][12] --------
__global__ __launch_bounds__(256) void k_e2(const float* __restrict__ emb,
                                            const float* __restrict__ w_ds2, // [256][768]
                                            float* __restrict__ e2T) {       // [64][768][12]
  const int bn0 = blockIdx.x * 2;            // bn0 even -> both rows same b
  const int b = bn0 / NN;
  const int n0 = bn0 - b * NN;
  const int t = threadIdx.x;
  float a00 = 0, a01 = 0, a02 = 0, a10 = 0, a11 = 0, a12 = 0;
#pragma unroll 4
  for (int o = 0; o < NFC; ++o) {
    const float w0 = w_ds2[(size_t)o * IMG_C + t];
    const float w1 = w_ds2[(size_t)o * IMG_C + t + 256];
    const float w2 = w_ds2[(size_t)o * IMG_C + t + 512];
    const float e0 = emb[(size_t)bn0 * NFC + o];        // uniform
    const float e1 = emb[(size_t)(bn0 + 1) * NFC + o];  // uniform
    a00 = fmaf(e0, w0, a00); a01 = fmaf(e0, w1, a01); a02 = fmaf(e0, w2, a02);
    a10 = fmaf(e1, w0, a10); a11 = fmaf(e1, w1, a11); a12 = fmaf(e1, w2, a12);
  }
  float* __restrict__ dst = e2T + (size_t)b * IMG_C * NN;
  dst[(size_t)t * NN + n0]              = a00;
  dst[(size_t)(t + 256) * NN + n0]      = a01;
  dst[(size_t)(t + 512) * NN + n0]      = a02;
  dst[(size_t)t * NN + n0 + 1]          = a10;
  dst[(size_t)(t + 256) * NN + n0 + 1]  = a11;
  dst[(size_t)(t + 512) * NN + n0 + 1]  = a12;
}

// ---------------- K4: online-softmax flash attention -------------------------
// Grid (NCH, BTB), 768 threads (12 waves), 2 blocks/CU. Per sub-tile of 120 s:
//   A: scores via 12-way K-split (thread = (kq, s-pair), float2 F loads)
//   reduce -> Ebuf, online max/rescale, E=exp(a-m), Z update
//   B: acc[n][c] += E*F, F re-read L3-hot (stripe read seconds-old, bounded)
// F is fetched from HBM exactly once; part merged by k_combine.
__global__ __launch_bounds__(768, 6) void k_attn_online(
    const float* __restrict__ F,      // [64][768][3600]
    const float* __restrict__ e2T,    // [64][768][12]
    float* __restrict__ part,         // [NCH][64][12][768]
    float* __restrict__ pm,           // [64][NCH][12]
    float* __restrict__ ps) {         // [64][NCH][12]
  __shared__ float a_part[12][12][121];              // [kq][n][s]  69.7 KB
  __shared__ __align__(16) float Ebuf[12][132];      // raw a, then E (pad 132)
  __shared__ float m_l[12], Z_l[12], r_l[12];
  const int b = blockIdx.y;
  const int ch = blockIdx.x;
  const int t = threadIdx.x;
  const float* __restrict__ Fb = F + (size_t)b * IMG_C * S_TOT;
  const float* __restrict__ e2b = e2T + (size_t)b * IMG_C * NN;

  if (t < 12) { m_l[t] = -3.0e38f; Z_l[t] = 0.f; }

  // phase-A ids: thread = (kq, s-pair), 720 active
  const int kq = t / 60, sp = t % 60;
  const bool aAct = (t < 720);
  // phase-B ids: wave owns 64 c; lane = (cl, n)
  const int w = t >> 6, lane = t & 63;
  const int cl = lane / 12, n_b = lane - cl * 12;    // cl<5 active
  const bool bAct = (cl < 5);
  const int cbase = w * 64;

  float acc[13];
#pragma unroll
  for (int g = 0; g < 13; ++g) acc[g] = 0.f;
  __syncthreads();

#pragma unroll 1
  for (int sub = 0; sub < NSUB; ++sub) {
    const int s0 = ch * SCH + sub * SUB;
    // ---- phase A: partial scores for this sub-tile ----
    if (aAct) {
      float a0[NN], a1[NN];
#pragma unroll
      for (int n = 0; n < NN; ++n) { a0[n] = 0.f; a1[n] = 0.f; }
      const int c0 = kq * 64;
#pragma unroll 4
      for (int c = 0; c < 64; ++c) {
        const float2 f = *reinterpret_cast<const float2*>(
            Fb + (size_t)(c0 + c) * S_TOT + s0 + 2 * sp);
        const float* e2c = e2b + (c0 + c) * NN;       // broadcast within kq group
        const float4 ea = *reinterpret_cast<const float4*>(e2c);
        const float4 eb = *reinterpret_cast<const float4*>(e2c + 4);
        const float4 ec = *reinterpret_cast<const float4*>(e2c + 8);
        a0[0] = fmaf(ea.x, f.x, a0[0]);  a1[0] = fmaf(ea.x, f.y, a1[0]);
        a0[1] = fmaf(ea.y, f.x, a0[1]);  a1[1] = fmaf(ea.y, f.y, a1[1]);
        a0[2] = fmaf(ea.z, f.x, a0[2]);  a1[2] = fmaf(ea.z, f.y, a1[2]);
        a0[3] = fmaf(ea.w, f.x, a0[3]);  a1[3] = fmaf(ea.w, f.y, a1[3]);
        a0[4] = fmaf(eb.x, f.x, a0[4]);  a1[4] = fmaf(eb.x, f.y, a1[4]);
        a0[5] = fmaf(eb.y, f.x, a0[5]);  a1[5] = fmaf(eb.y, f.y, a1[5]);
        a0[6] = fmaf(eb.z, f.x, a0[6]);  a1[6] = fmaf(eb.z, f.y, a1[6]);
        a0[7] = fmaf(eb.w, f.x, a0[7]);  a1[7] = fmaf(eb.w, f.y, a1[7]);
        a0[8] = fmaf(ec.x, f.x, a0[8]);  a1[8] = fmaf(ec.x, f.y, a1[8]);
        a0[9] = fmaf(ec.y, f.x, a0[9]);  a1[9] = fmaf(ec.y, f.y, a1[9]);
        a0[10] = fmaf(ec.z, f.x, a0[10]); a1[10] = fmaf(ec.z, f.y, a1[10]);
        a0[11] = fmaf(ec.w, f.x, a0[11]); a1[11] = fmaf(ec.w, f.y, a1[11]);
      }
#pragma unroll
      for (int n = 0; n < NN; ++n) {
        a_part[kq][n][2 * sp]     = a0[n];
        a_part[kq][n][2 * sp + 1] = a1[n];
      }
    }
    __syncthreads();
    // ---- reduce 12 partials -> Ebuf (raw scores) ----
#pragma unroll
    for (int pi = 0; pi < 2; ++pi) {
      const int p = t + pi * 768;
      if (p < NN * SUB) {
        const int n = p / SUB, s = p - n * SUB;
        float v = 0.f;
#pragma unroll
        for (int k2 = 0; k2 < 12; ++k2) v += a_part[k2][n][s];
        Ebuf[n][s] = v;
      }
    }
    __syncthreads();
    // ---- per-n tile max (wave w handles n=w), online m/r update ----
    {
      float v = Ebuf[w][lane];
      if (lane < SUB - 64) v = fmaxf(v, Ebuf[w][64 + lane]);
#pragma unroll
      for (int off = 32; off > 0; off >>= 1) v = fmaxf(v, __shfl_xor(v, off, 64));
      if (lane == 0) {
        const float mo = m_l[w];
        const float mn = fmaxf(mo, v);
        m_l[w] = mn;
        r_l[w] = expf(mo - mn);            // first sub: exp(-3e38-mn)=0
      }
    }
    __syncthreads();
    // ---- E = exp(a - m) in place ----
#pragma unroll
    for (int pi = 0; pi < 2; ++pi) {
      const int p = t + pi * 768;
      if (p < NN * SUB) {
        const int n = p / SUB, s = p - n * SUB;
        Ebuf[n][s] = expf(Ebuf[n][s] - m_l[n]);
      }
    }
    __syncthreads();
    // ---- Z update (wave-per-n) ----
    {
      float v = Ebuf[w][lane];
      if (lane < SUB - 64) v += Ebuf[w][64 + lane];
#pragma unroll
      for (int off = 32; off > 0; off >>= 1) v += __shfl_xor(v, off, 64);
      if (lane == 0) Z_l[w] = Z_l[w] * r_l[w] + v;
    }
    // ---- phase B: rescale acc, accumulate this sub (F re-read, L3-hot) ----
    if (bAct) {
      const float rr = r_l[n_b];
#pragma unroll
      for (int g = 0; g < 13; ++g) acc[g] *= rr;
      const float* __restrict__ FB = Fb + (size_t)cbase * S_TOT + s0;
#pragma unroll 2
      for (int s4 = 0; s4 < SUB / 4; ++s4) {
        const float4 e = *reinterpret_cast<const float4*>(&Ebuf[n_b][4 * s4]);
#pragma unroll
        for (int g = 0; g < 12; ++g) {
          const float4 f = *reinterpret_cast<const float4*>(
              FB + (size_t)(g * 5 + cl) * S_TOT + 4 * s4);
          acc[g] = fmaf(e.x, f.x, fmaf(e.y, f.y, fmaf(e.z, f.z, fmaf(e.w, f.w, acc[g]))));
        }
        if (cl < 4) {
          const float4 f = *reinterpret_cast<const float4*>(
              FB + (size_t)(60 + cl) * S_TOT + 4 * s4);
          acc[12] = fmaf(e.x, f.x, fmaf(e.y, f.y, fmaf(e.z, f.z, fmaf(e.w, f.w, acc[12]))));
        }
      }
    }
    __syncthreads();   // protect a_part/Ebuf overwrite next sub
  }

  // ---- writeout ----
  if (bAct) {
    float* __restrict__ dst = part + (((size_t)ch * BTB + b) * NN + n_b) * IMG_C;
#pragma unroll
    for (int g = 0; g < 12; ++g) dst[cbase + g * 5 + cl] = acc[g];
    if (cl < 4) dst[cbase + 60 + cl] = acc[12];
  }
  if (t < 12) {
    pm[((size_t)b * NCH + ch) * NN + t] = m_l[t];
    ps[((size_t)b * NCH + ch) * NN + t] = Z_l[t];
  }
}

// ---------------- K5: combine chunk partials -> ctx768 -----------------------
__global__ __launch_bounds__(256) void k_combine(
    const float* __restrict__ part, const float* __restrict__ pm,
    const float* __restrict__ ps, float* __restrict__ ctx768) {  // [BN][768]
  const int bn = blockIdx.x;            // b*12+n
  const int b = bn / NN, n = bn - b * NN;
  const int t = threadIdx.x;
  float mv[NCH];
  float m = -3.0e38f;
#pragma unroll
  for (int ch = 0; ch < NCH; ++ch) {
    mv[ch] = pm[((size_t)b * NCH + ch) * NN + n];
    m = fmaxf(m, mv[ch]);
  }
  float Z = 0.f, al[NCH];
#pragma unroll
  for (int ch = 0; ch < NCH; ++ch) {
    al[ch] = expf(mv[ch] - m);
    Z += ps[((size_t)b * NCH + ch) * NN + n] * al[ch];
  }
  const float rz = 1.0f / Z;
#pragma unroll 1
  for (int ci = 0; ci < 3; ++ci) {
    const int c = ci * 256 + t;
    float s = 0.f;
#pragma unroll
    for (int ch = 0; ch < NCH; ++ch)
      s += part[(((size_t)ch * BTB + b) * NN + n) * IMG_C + c] * al[ch];
    ctx768[(size_t)bn * IMG_C + c] = s * rz;
  }
}

// ---------------- K6: ctx = W_ds2 . ctx768 + b_ds2, +emb residual, LN1 -------
__global__ __launch_bounds__(256) void k_ctx_ln1(
    const float* __restrict__ ctx768, const float* __restrict__ wds2T, // [768][256]
    const float* __restrict__ b_ds2, const float* __restrict__ emb,
    const float* __restrict__ g, const float* __restrict__ be,
    float* __restrict__ x) {
  __shared__ float sm[4];
  const int r0 = blockIdx.x * 3;
  const int o = threadIdx.x;
  float acc[3] = {0.f, 0.f, 0.f};
#pragma unroll 2
  for (int cc = 0; cc < IMG_C; ++cc) {
    const float w = wds2T[(size_t)cc * NFC + o];
#pragma unroll
    for (int r = 0; r < 3; ++r)
      acc[r] = fmaf(w, ctx768[(size_t)(r0 + r) * IMG_C + cc], acc[r]);  // uniform
  }
  const float bv = b_ds2[o], gv = g[o], bev = be[o];
#pragma unroll 1
  for (int r = 0; r < 3; ++r) {
    const float val = acc[r] + bv + emb[(size_t)(r0 + r) * NFC + o];
    const float mu = blockSum256(val, sm) * (1.0f / NFC);
    const float d = val - mu;
    const float var = blockSum256(d * d, sm) * (1.0f / NFC);
    x[(size_t)(r0 + r) * NFC + o] = d * rsqrtf(var + LN_EPS) * gv + bev;
  }
}

// ---------------- K7: FFN + residual + LN2 -----------------------------------
__global__ __launch_bounds__(256) void k_ffn_ln2(const float* __restrict__ x,
                                                 const float* __restrict__ w1T,
                                                 const float* __restrict__ b1,
                                                 const float* __restrict__ w2T,
                                                 const float* __restrict__ b2,
                                                 const float* __restrict__ g2,
                                                 const float* __restrict__ be2,
                                                 float* __restrict__ out) {
  __shared__ float hs[3][NFC];
  __shared__ float sm[4];
  const int r0 = blockIdx.x * 3;
  const int o = threadIdx.x;
  float acc[3] = {0.f, 0.f, 0.f};
#pragma unroll 4
  for (int c = 0; c < NFC; ++c) {
    const float w = w1T[(size_t)c * NFC + o];
#pragma unroll
    for (int r = 0; r < 3; ++r)
      acc[r] = fmaf(w, x[(size_t)(r0 + r) * NFC + c], acc[r]);
  }
  const float bb = b1[o];
#pragma unroll
  for (int r = 0; r < 3; ++r) hs[r][o] = fmaxf(acc[r] + bb, 0.0f);
  __syncthreads();
  float acc2[3] = {0.f, 0.f, 0.f};
#pragma unroll 4
  for (int c = 0; c < NFC; ++c) {
    const float w = w2T[(size_t)c * NFC + o];
#pragma unroll
    for (int r = 0; r < 3; ++r) acc2[r] = fmaf(w, hs[r][c], acc2[r]);
  }
  const float b2v = b2[o], gv = g2[o], bev = be2[o];
#pragma unroll 1
  for (int r = 0; r < 3; ++r) {
    const float val = acc2[r] + b2v + x[(size_t)(r0 + r) * NFC + o];
    const float mu = blockSum256(val, sm) * (1.0f / NFC);
    const float d = val - mu;
    const float var = blockSum256(d * d, sm) * (1.0f / NFC);
    out[(size_t)(r0 + r) * NFC + o] = d * rsqrtf(var + LN_EPS) * gv + bev;
  }
}

// ---------------- launch -----------------------------------------------------
extern "C" void kernel_launch(void* const* d_in, const int* in_sizes, int n_in,
                              void* d_out, int out_size, void* d_ws, size_t ws_size,
                              hipStream_t stream) {
  const float* roi_feature   = (const float*)d_in[0];
  const float* image_feature = (const float*)d_in[1];
  const float* w_ds1  = (const float*)d_in[2];
  const float* b_ds1  = (const float*)d_in[3];
  const float* w_ds2  = (const float*)d_in[4];
  const float* b_ds2  = (const float*)d_in[5];
  const float* w_emb  = (const float*)d_in[6];
  const float* b_emb  = (const float*)d_in[7];
  const float* g1     = (const float*)d_in[8];
  const float* be1    = (const float*)d_in[9];
  const float* ffn_w1 = (const float*)d_in[10];
  const float* ffn_b1 = (const float*)d_in[11];
  const float* ffn_w2 = (const float*)d_in[12];
  const float* ffn_b2 = (const float*)d_in[13];
  const float* g2     = (const float*)d_in[14];
  const float* be2    = (const float*)d_in[15];
  float* out = (float*)d_out;

  float* p = (float*)d_ws;
  float* w1T    = p;   p += 1024 * 256;
  float* wembT  = p;   p += 6400 * 256;
  float* wds2T  = p;   p += 768 * 256;
  float* w1Tf   = p;   p += 256 * 256;
  float* w2Tf   = p;   p += 256 * 256;
  float* roi_ds = p;   p += 768 * 6400;
  float* emb_part = p; p += 8 * 768 * 256;
  float* emb    = p;   p += 768 * 256;
  float* e2T    = p;   p += 768 * 768;                     // [64][768][12]
  float* part   = p;   p += (size_t)NCH * BTB * NN * IMG_C;  // 5.9M floats
  float* pm     = p;   p += BTB * NCH * NN;
  float* ps     = p;   p += BTB * NCH * NN;
  float* ctx768 = p;   p += 768 * 768;
  float* xb     = p;   p += 768 * 256;

  k_transpose_all<<<544, 256, 0, stream>>>(w_ds1, w_emb, w_ds2, ffn_w1, ffn_w2,
                                           w1T, wembT, wds2T, w1Tf, w2Tf);
  k_ds1<<<BN, 256, 0, stream>>>(roi_feature, w1T, b_ds1, roi_ds);
  k_emb_part<<<dim3(48, 8), 256, 0, stream>>>(roi_ds, wembT, emb_part);
  k_emb_reduce<<<768, 256, 0, stream>>>(emb_part, b_emb, emb);
  k_e2<<<384, 256, 0, stream>>>(emb, w_ds2, e2T);
  k_attn_online<<<dim3(NCH, BTB), 768, 0, stream>>>(image_feature, e2T, part, pm, ps);
  k_combine<<<768, 256, 0, stream>>>(part, pm, ps, ctx768);
  k_ctx_ln1<<<256, 256, 0, stream>>>(ctx768, wds2T, b_ds2, emb, g1, be1, xb);
  k_ffn_ln2<<<256, 256, 0, stream>>>(xb, w1Tf, ffn_b1, w2Tf, ffn_b2, g2, be2, out);
}

// Round 4
// 1557.554 us; speedup vs baseline: 2.1511x; 2.1511x over previous
//
#include <hip/hip_runtime.h>

#define NFC   256
#define DIMD  1024
#define NN    12
#define BTB   64
#define S_TOT 3600
#define BN    768        // BT*N
#define EMB_K 6400       // NFC*5*5
#define IMG_C 768
#define LN_EPS 1e-5f
#define NCH   8          // chunks per b; ch<7: 28 stripes, ch7: 29 (225 total)
#define SW    16         // stripe width (64B rows -> perfect sectors)
#define FPAD  20         // F_lds row stride in words (80B, 16B-aligned, not pow2)

// ---------------- reduction helpers (block = 256 threads = 4 waves) ----------
__device__ __forceinline__ float waveSum(float v) {
#pragma unroll
  for (int off = 32; off > 0; off >>= 1) v += __shfl_down(v, off, 64);
  return v;
}
__device__ __forceinline__ float blockSum256(float v, float* sm) {
  v = waveSum(v);
  __syncthreads();
  if ((threadIdx.x & 63) == 0) sm[threadIdx.x >> 6] = v;
  __syncthreads();
  return sm[0] + sm[1] + sm[2] + sm[3];
}

// ---------------- K0: tiled weight transposes [256][Cin] -> [Cin][256] -------
__global__ __launch_bounds__(256) void k_transpose_all(
    const float* __restrict__ w_ds1, const float* __restrict__ w_emb,
    const float* __restrict__ w_ds2, const float* __restrict__ f1,
    const float* __restrict__ f2,
    float* __restrict__ w1T, float* __restrict__ wembT,
    float* __restrict__ wds2T, float* __restrict__ w1Tf,
    float* __restrict__ w2Tf) {
  __shared__ float tile[64][65];
  const int blk = blockIdx.x;
  const float* in; float* out; int Cin; int rel;
  if (blk < 64)       { in = w_ds1; out = w1T;   Cin = 1024; rel = blk; }
  else if (blk < 464) { in = w_emb; out = wembT; Cin = 6400; rel = blk - 64; }
  else if (blk < 512) { in = w_ds2; out = wds2T; Cin = 768;  rel = blk - 464; }
  else if (blk < 528) { in = f1;    out = w1Tf;  Cin = 256;  rel = blk - 512; }
  else                { in = f2;    out = w2Tf;  Cin = 256;  rel = blk - 528; }
  const int jt = Cin >> 6;
  const int i0 = (rel / jt) << 6;
  const int j0 = (rel % jt) << 6;
  const int tx = threadIdx.x & 63, ty = threadIdx.x >> 6;
#pragma unroll
  for (int k = 0; k < 16; ++k) {
    const int i = ty + k * 4;
    tile[i][tx] = in[(size_t)(i0 + i) * Cin + j0 + tx];
  }
  __syncthreads();
#pragma unroll
  for (int k = 0; k < 16; ++k) {
    const int j = ty + k * 4;
    out[(size_t)(j0 + j) * 256 + i0 + tx] = tile[tx][j];
  }
}

// ---------------- K1: ROI downsample1 ----------------------------------------
__global__ __launch_bounds__(256) void k_ds1(const float* __restrict__ RF,   // [BN][1024][25]
                                             const float* __restrict__ w1T,  // [1024][256]
                                             const float* __restrict__ b1,
                                             float* __restrict__ roi_ds) {   // [BN][6400]
  const int r = blockIdx.x;
  const int c = threadIdx.x;
  const float* __restrict__ rf = RF + (size_t)r * (DIMD * 25);
  float acc[25];
#pragma unroll
  for (int p = 0; p < 25; ++p) acc[p] = 0.f;
#pragma unroll 2
  for (int d = 0; d < DIMD; ++d) {
    const float w = w1T[(size_t)d * NFC + c];
#pragma unroll
    for (int p = 0; p < 25; ++p)
      acc[p] = fmaf(w, rf[d * 25 + p], acc[p]);
  }
  const float bias = b1[c];
  float* out = roi_ds + (size_t)r * EMB_K + c * 25;
#pragma unroll
  for (int p = 0; p < 25; ++p) out[p] = acc[p] + bias;
}

// ---------------- K2: emb partial GEMM, k-split 8 ----------------------------
__global__ __launch_bounds__(256) void k_emb_part(const float* __restrict__ roi_ds,
                                                  const float* __restrict__ wembT,
                                                  float* __restrict__ emb_part) { // [8][BN][256]
  const int r0 = blockIdx.x * 16;
  const int kz = blockIdx.y;
  const int c = threadIdx.x;
  const int k0 = kz * (EMB_K / 8);
  float acc[16];
#pragma unroll
  for (int r = 0; r < 16; ++r) acc[r] = 0.f;
#pragma unroll 4
  for (int k = k0; k < k0 + EMB_K / 8; ++k) {
    const float w = wembT[(size_t)k * NFC + c];
#pragma unroll
    for (int r = 0; r < 16; ++r)
      acc[r] = fmaf(w, roi_ds[(size_t)(r0 + r) * EMB_K + k], acc[r]);
  }
#pragma unroll
  for (int r = 0; r < 16; ++r)
    emb_part[((size_t)kz * BN + r0 + r) * NFC + c] = acc[r];
}

__global__ __launch_bounds__(256) void k_emb_reduce(const float* __restrict__ emb_part,
                                                    const float* __restrict__ bemb,
                                                    float* __restrict__ emb) {
  int i = blockIdx.x * 256 + threadIdx.x;
  float s = bemb[i & 255];
#pragma unroll
  for (int z = 0; z < 8; ++z) s += emb_part[(size_t)z * BN * NFC + i];
  emb[i] = s;
}

// ---------------- K3: e2T = (emb @ w_ds2) transposed to [64][768][12] --------
__global__ __launch_bounds__(256) void k_e2(const float* __restrict__ emb,
                                            const float* __restrict__ w_ds2, // [256][768]
                                            float* __restrict__ e2T) {       // [64][768][12]
  const int bn0 = blockIdx.x * 2;            // bn0 even -> both rows same b
  const int b = bn0 / NN;
  const int n0 = bn0 - b * NN;
  const int t = threadIdx.x;
  float a00 = 0, a01 = 0, a02 = 0, a10 = 0, a11 = 0, a12 = 0;
#pragma unroll 4
  for (int o = 0; o < NFC; ++o) {
    const float w0 = w_ds2[(size_t)o * IMG_C + t];
    const float w1 = w_ds2[(size_t)o * IMG_C + t + 256];
    const float w2 = w_ds2[(size_t)o * IMG_C + t + 512];
    const float e0 = emb[(size_t)bn0 * NFC + o];
    const float e1 = emb[(size_t)(bn0 + 1) * NFC + o];
    a00 = fmaf(e0, w0, a00); a01 = fmaf(e0, w1, a01); a02 = fmaf(e0, w2, a02);
    a10 = fmaf(e1, w0, a10); a11 = fmaf(e1, w1, a11); a12 = fmaf(e1, w2, a12);
  }
  float* __restrict__ dst = e2T + (size_t)b * IMG_C * NN;
  dst[(size_t)t * NN + n0]              = a00;
  dst[(size_t)(t + 256) * NN + n0]      = a01;
  dst[(size_t)(t + 512) * NN + n0]      = a02;
  dst[(size_t)t * NN + n0 + 1]          = a10;
  dst[(size_t)(t + 256) * NN + n0 + 1]  = a11;
  dst[(size_t)(t + 512) * NN + n0 + 1]  = a12;
}

// ---------------- K4: flash attention, F -> HBM exactly once -----------------
// Grid (8, 64), 768 threads (12 waves), 2 blocks/CU.  Per 16-column stripe:
//  A: wave w owns c in [64w,64w+64); lane=(nq,s). One 64B coalesced F read
//     per c (lane-duplicated x4, hw-merged), 3 e2 loads (L2), 3 FMAs; nq==0
//     lanes copy F to LDS. F touches HBM exactly once by construction.
//  reduce 12 wave-partials -> online softmax (192 threads, 16-lane groups)
//  B: thread=c; F row from LDS (4x b128), E broadcast, 192 FMA into acc[12].
__global__ __launch_bounds__(768, 6) void k_attn_flash(
    const float* __restrict__ F,      // [64][768][3600]
    const float* __restrict__ e2T,    // [64][768][12]
    float* __restrict__ part,         // [NCH][64][12][768]
    float* __restrict__ pm,           // [64][NCH][12]
    float* __restrict__ ps) {         // [64][NCH][12]
  __shared__ __align__(16) float F_lds[IMG_C * FPAD];   // 61.4 KB
  __shared__ float a_part[12 * NN * SW];                // 9.2 KB
  __shared__ __align__(16) float E_lds[NN * SW];        // 768 B
  __shared__ float m_l[NN], Z_l[NN], r_l[NN];
  const int b = blockIdx.y;
  const int ch = blockIdx.x;
  const int t = threadIdx.x;
  const int w = t >> 6, lane = t & 63;
  const int nq = lane >> 4, s = lane & 15;
  const int c0 = w * 64;
  const float* __restrict__ Fb = F + (size_t)b * IMG_C * S_TOT;
  const float* __restrict__ e2b = e2T + (size_t)b * IMG_C * NN;

  if (t < NN) { m_l[t] = -3.0e38f; Z_l[t] = 0.f; }
  float acc[NN];
#pragma unroll
  for (int n = 0; n < NN; ++n) acc[n] = 0.f;
  __syncthreads();

  const int nsub = (ch == NCH - 1) ? 29 : 28;
#pragma unroll 1
  for (int sub = 0; sub < nsub; ++sub) {
    const int s0 = ch * 448 + sub * SW;
    // ---- phase A ----
    float a0 = 0.f, a1 = 0.f, a2 = 0.f;
    {
      const float* __restrict__ Fp = Fb + (size_t)c0 * S_TOT + s0 + s;
      const float* __restrict__ ep = e2b + c0 * NN + nq * 3;
      float* __restrict__ Fw = &F_lds[c0 * FPAD + s];
#pragma unroll 4
      for (int ci = 0; ci < 64; ++ci) {
        const float f = Fp[(size_t)ci * S_TOT];
        const float e0 = ep[ci * NN + 0];
        const float e1 = ep[ci * NN + 1];
        const float e2v = ep[ci * NN + 2];
        a0 = fmaf(e0, f, a0);
        a1 = fmaf(e1, f, a1);
        a2 = fmaf(e2v, f, a2);
        if (nq == 0) Fw[ci * FPAD] = f;
      }
    }
    {
      float* ap = &a_part[(w * NN + nq * 3) * SW + s];
      ap[0] = a0; ap[SW] = a1; ap[2 * SW] = a2;
    }
    __syncthreads();
    // ---- reduce + online softmax (threads 0..191) ----
    if (t < NN * SW) {
      const int n = t >> 4, si = t & 15;
      float v = 0.f;
#pragma unroll
      for (int ww = 0; ww < 12; ++ww) v += a_part[ww * NN * SW + t];
      float mt = v;
#pragma unroll
      for (int off = 1; off < 16; off <<= 1) mt = fmaxf(mt, __shfl_xor(mt, off, 64));
      const float mo = m_l[n];
      const float mn = fmaxf(mo, mt);
      const float rr = expf(mo - mn);          // 0 on first stripe
      const float ev = expf(v - mn);
      E_lds[n * SW + si] = ev;
      float zs = ev;
#pragma unroll
      for (int off = 1; off < 16; off <<= 1) zs += __shfl_xor(zs, off, 64);
      if (si == 0) { m_l[n] = mn; r_l[n] = rr; Z_l[n] = Z_l[n] * rr + zs; }
    }
    __syncthreads();
    // ---- phase B: thread = c, F row from LDS ----
    {
#pragma unroll
      for (int n = 0; n < NN; ++n) acc[n] *= r_l[n];
      const float* __restrict__ Fr = &F_lds[t * FPAD];
      const float4 f0 = *reinterpret_cast<const float4*>(Fr + 0);
      const float4 f1 = *reinterpret_cast<const float4*>(Fr + 4);
      const float4 f2 = *reinterpret_cast<const float4*>(Fr + 8);
      const float4 f3 = *reinterpret_cast<const float4*>(Fr + 12);
#pragma unroll
      for (int n = 0; n < NN; ++n) {
        const float4 e0 = *reinterpret_cast<const float4*>(&E_lds[n * SW + 0]);
        const float4 e1 = *reinterpret_cast<const float4*>(&E_lds[n * SW + 4]);
        const float4 e2q = *reinterpret_cast<const float4*>(&E_lds[n * SW + 8]);
        const float4 e3 = *reinterpret_cast<const float4*>(&E_lds[n * SW + 12]);
        float d = fmaf(e0.x, f0.x, fmaf(e0.y, f0.y, fmaf(e0.z, f0.z, e0.w * f0.w)));
        d = fmaf(e1.x, f1.x, fmaf(e1.y, f1.y, fmaf(e1.z, f1.z, fmaf(e1.w, f1.w, d))));
        d = fmaf(e2q.x, f2.x, fmaf(e2q.y, f2.y, fmaf(e2q.z, f2.z, fmaf(e2q.w, f2.w, d))));
        d = fmaf(e3.x, f3.x, fmaf(e3.y, f3.y, fmaf(e3.z, f3.z, fmaf(e3.w, f3.w, d))));
        acc[n] += d;
      }
    }
    __syncthreads();   // protect F_lds/a_part/E_lds for next stripe
  }

  // ---- writeout ----
  {
    float* __restrict__ dst = part + (((size_t)ch * BTB + b) * NN) * IMG_C + t;
#pragma unroll
    for (int n = 0; n < NN; ++n) dst[(size_t)n * IMG_C] = acc[n];
  }
  if (t < NN) {
    pm[((size_t)b * NCH + ch) * NN + t] = m_l[t];
    ps[((size_t)b * NCH + ch) * NN + t] = Z_l[t];
  }
}

// ---------------- K5: combine chunk partials -> ctx768 -----------------------
__global__ __launch_bounds__(256) void k_combine(
    const float* __restrict__ part, const float* __restrict__ pm,
    const float* __restrict__ ps, float* __restrict__ ctx768) {  // [BN][768]
  const int bn = blockIdx.x;            // b*12+n
  const int b = bn / NN, n = bn - b * NN;
  const int t = threadIdx.x;
  float mv[NCH];
  float m = -3.0e38f;
#pragma unroll
  for (int ch = 0; ch < NCH; ++ch) {
    mv[ch] = pm[((size_t)b * NCH + ch) * NN + n];
    m = fmaxf(m, mv[ch]);
  }
  float Z = 0.f, al[NCH];
#pragma unroll
  for (int ch = 0; ch < NCH; ++ch) {
    al[ch] = expf(mv[ch] - m);
    Z += ps[((size_t)b * NCH + ch) * NN + n] * al[ch];
  }
  const float rz = 1.0f / Z;
#pragma unroll 1
  for (int ci = 0; ci < 3; ++ci) {
    const int c = ci * 256 + t;
    float s = 0.f;
#pragma unroll
    for (int ch = 0; ch < NCH; ++ch)
      s += part[(((size_t)ch * BTB + b) * NN + n) * IMG_C + c] * al[ch];
    ctx768[(size_t)bn * IMG_C + c] = s * rz;
  }
}

// ---------------- K6: ctx = W_ds2 . ctx768 + b_ds2, +emb residual, LN1 -------
__global__ __launch_bounds__(256) void k_ctx_ln1(
    const float* __restrict__ ctx768, const float* __restrict__ wds2T, // [768][256]
    const float* __restrict__ b_ds2, const float* __restrict__ emb,
    const float* __restrict__ g, const float* __restrict__ be,
    float* __restrict__ x) {
  __shared__ float sm[4];
  const int r0 = blockIdx.x * 3;
  const int o = threadIdx.x;
  float acc[3] = {0.f, 0.f, 0.f};
#pragma unroll 2
  for (int cc = 0; cc < IMG_C; ++cc) {
    const float w = wds2T[(size_t)cc * NFC + o];
#pragma unroll
    for (int r = 0; r < 3; ++r)
      acc[r] = fmaf(w, ctx768[(size_t)(r0 + r) * IMG_C + cc], acc[r]);
  }
  const float bv = b_ds2[o], gv = g[o], bev = be[o];
#pragma unroll 1
  for (int r = 0; r < 3; ++r) {
    const float val = acc[r] + bv + emb[(size_t)(r0 + r) * NFC + o];
    const float mu = blockSum256(val, sm) * (1.0f / NFC);
    const float d = val - mu;
    const float var = blockSum256(d * d, sm) * (1.0f / NFC);
    x[(size_t)(r0 + r) * NFC + o] = d * rsqrtf(var + LN_EPS) * gv + bev;
  }
}

// ---------------- K7: FFN + residual + LN2 -----------------------------------
__global__ __launch_bounds__(256) void k_ffn_ln2(const float* __restrict__ x,
                                                 const float* __restrict__ w1T,
                                                 const float* __restrict__ b1,
                                                 const float* __restrict__ w2T,
                                                 const float* __restrict__ b2,
                                                 const float* __restrict__ g2,
                                                 const float* __restrict__ be2,
                                                 float* __restrict__ out) {
  __shared__ float hs[3][NFC];
  __shared__ float sm[4];
  const int r0 = blockIdx.x * 3;
  const int o = threadIdx.x;
  float acc[3] = {0.f, 0.f, 0.f};
#pragma unroll 4
  for (int c = 0; c < NFC; ++c) {
    const float w = w1T[(size_t)c * NFC + o];
#pragma unroll
    for (int r = 0; r < 3; ++r)
      acc[r] = fmaf(w, x[(size_t)(r0 + r) * NFC + c], acc[r]);
  }
  const float bb = b1[o];
#pragma unroll
  for (int r = 0; r < 3; ++r) hs[r][o] = fmaxf(acc[r] + bb, 0.0f);
  __syncthreads();
  float acc2[3] = {0.f, 0.f, 0.f};
#pragma unroll 4
  for (int c = 0; c < NFC; ++c) {
    const float w = w2T[(size_t)c * NFC + o];
#pragma unroll
    for (int r = 0; r < 3; ++r) acc2[r] = fmaf(w, hs[r][c], acc2[r]);
  }
  const float b2v = b2[o], gv = g2[o], bev = be2[o];
#pragma unroll 1
  for (int r = 0; r < 3; ++r) {
    const float val = acc2[r] + b2v + x[(size_t)(r0 + r) * NFC + o];
    const float mu = blockSum256(val, sm) * (1.0f / NFC);
    const float d = val - mu;
    const float var = blockSum256(d * d, sm) * (1.0f / NFC);
    out[(size_t)(r0 + r) * NFC + o] = d * rsqrtf(var + LN_EPS) * gv + bev;
  }
}

// ---------------- launch -----------------------------------------------------
extern "C" void kernel_launch(void* const* d_in, const int* in_sizes, int n_in,
                              void* d_out, int out_size, void* d_ws, size_t ws_size,
                              hipStream_t stream) {
  const float* roi_feature   = (const float*)d_in[0];
  const float* image_feature = (const float*)d_in[1];
  const float* w_ds1  = (const float*)d_in[2];
  const float* b_ds1  = (const float*)d_in[3];
  const float* w_ds2  = (const float*)d_in[4];
  const float* b_ds2  = (const float*)d_in[5];
  const float* w_emb  = (const float*)d_in[6];
  const float* b_emb  = (const float*)d_in[7];
  const float* g1     = (const float*)d_in[8];
  const float* be1    = (const float*)d_in[9];
  const float* ffn_w1 = (const float*)d_in[10];
  const float* ffn_b1 = (const float*)d_in[11];
  const float* ffn_w2 = (const float*)d_in[12];
  const float* ffn_b2 = (const float*)d_in[13];
  const float* g2     = (const float*)d_in[14];
  const float* be2    = (const float*)d_in[15];
  float* out = (float*)d_out;

  float* p = (float*)d_ws;
  float* w1T    = p;   p += 1024 * 256;
  float* wembT  = p;   p += 6400 * 256;
  float* wds2T  = p;   p += 768 * 256;
  float* w1Tf   = p;   p += 256 * 256;
  float* w2Tf   = p;   p += 256 * 256;
  float* roi_ds = p;   p += 768 * 6400;
  float* emb_part = p; p += 8 * 768 * 256;
  float* emb    = p;   p += 768 * 256;
  float* e2T    = p;   p += 768 * 768;                       // [64][768][12]
  float* part   = p;   p += (size_t)NCH * BTB * NN * IMG_C;  // 4.72M floats
  float* pm     = p;   p += BTB * NCH * NN;
  float* ps     = p;   p += BTB * NCH * NN;
  float* ctx768 = p;   p += 768 * 768;
  float* xb     = p;   p += 768 * 256;

  k_transpose_all<<<544, 256, 0, stream>>>(w_ds1, w_emb, w_ds2, ffn_w1, ffn_w2,
                                           w1T, wembT, wds2T, w1Tf, w2Tf);
  k_ds1<<<BN, 256, 0, stream>>>(roi_feature, w1T, b_ds1, roi_ds);
  k_emb_part<<<dim3(48, 8), 256, 0, stream>>>(roi_ds, wembT, emb_part);
  k_emb_reduce<<<768, 256, 0, stream>>>(emb_part, b_emb, emb);
  k_e2<<<384, 256, 0, stream>>>(emb, w_ds2, e2T);
  k_attn_flash<<<dim3(NCH, BTB), 768, 0, stream>>>(image_feature, e2T, part, pm, ps);
  k_combine<<<768, 256, 0, stream>>>(part, pm, ps, ctx768);
  k_ctx_ln1<<<256, 256, 0, stream>>>(ctx768, wds2T, b_ds2, emb, g1, be1, xb);
  k_ffn_ln2<<<256, 256, 0, stream>>>(xb, w1Tf, ffn_b1, w2Tf, ffn_b2, g2, be2, out);
}

// Round 5
// 1161.306 us; speedup vs baseline: 2.8851x; 1.3412x over previous
//
#include <hip/hip_runtime.h>

#define NFC   256
#define DIMD  1024
#define NN    12
#define BTB   64
#define S_TOT 3600
#define BN    768        // BT*N
#define EMB_K 6400       // NFC*5*5
#define IMG_C 768
#define LN_EPS 1e-5f
#define NCH   8          // chunks per b; ch<7: 28 stripes, ch7: 29 (225 total)
#define SW    16         // stripe width (64B rows -> perfect sectors)
#define FPAD  20         // F_lds row stride in words (80B, 16B-aligned, not pow2)

// ---------------- reduction helpers (block = 256 threads = 4 waves) ----------
__device__ __forceinline__ float waveSum(float v) {
#pragma unroll
  for (int off = 32; off > 0; off >>= 1) v += __shfl_down(v, off, 64);
  return v;
}
__device__ __forceinline__ float blockSum256(float v, float* sm) {
  v = waveSum(v);
  __syncthreads();
  if ((threadIdx.x & 63) == 0) sm[threadIdx.x >> 6] = v;
  __syncthreads();
  return sm[0] + sm[1] + sm[2] + sm[3];
}

// ---------------- K0: tiled weight transposes [256][Cin] -> [Cin][256] -------
__global__ __launch_bounds__(256) void k_transpose_all(
    const float* __restrict__ w_ds1, const float* __restrict__ w_emb,
    const float* __restrict__ w_ds2, const float* __restrict__ f1,
    const float* __restrict__ f2,
    float* __restrict__ w1T, float* __restrict__ wembT,
    float* __restrict__ wds2T, float* __restrict__ w1Tf,
    float* __restrict__ w2Tf) {
  __shared__ float tile[64][65];
  const int blk = blockIdx.x;
  const float* in; float* out; int Cin; int rel;
  if (blk < 64)       { in = w_ds1; out = w1T;   Cin = 1024; rel = blk; }
  else if (blk < 464) { in = w_emb; out = wembT; Cin = 6400; rel = blk - 64; }
  else if (blk < 512) { in = w_ds2; out = wds2T; Cin = 768;  rel = blk - 464; }
  else if (blk < 528) { in = f1;    out = w1Tf;  Cin = 256;  rel = blk - 512; }
  else                { in = f2;    out = w2Tf;  Cin = 256;  rel = blk - 528; }
  const int jt = Cin >> 6;
  const int i0 = (rel / jt) << 6;
  const int j0 = (rel % jt) << 6;
  const int tx = threadIdx.x & 63, ty = threadIdx.x >> 6;
#pragma unroll
  for (int k = 0; k < 16; ++k) {
    const int i = ty + k * 4;
    tile[i][tx] = in[(size_t)(i0 + i) * Cin + j0 + tx];
  }
  __syncthreads();
#pragma unroll
  for (int k = 0; k < 16; ++k) {
    const int j = ty + k * 4;
    out[(size_t)(j0 + j) * 256 + i0 + tx] = tile[tx][j];
  }
}

// ---------------- K1: ROI downsample1 ----------------------------------------
__global__ __launch_bounds__(256) void k_ds1(const float* __restrict__ RF,   // [BN][1024][25]
                                             const float* __restrict__ w1T,  // [1024][256]
                                             const float* __restrict__ b1,
                                             float* __restrict__ roi_ds) {   // [BN][6400]
  const int r = blockIdx.x;
  const int c = threadIdx.x;
  const float* __restrict__ rf = RF + (size_t)r * (DIMD * 25);
  float acc[25];
#pragma unroll
  for (int p = 0; p < 25; ++p) acc[p] = 0.f;
#pragma unroll 2
  for (int d = 0; d < DIMD; ++d) {
    const float w = w1T[(size_t)d * NFC + c];
#pragma unroll
    for (int p = 0; p < 25; ++p)
      acc[p] = fmaf(w, rf[d * 25 + p], acc[p]);
  }
  const float bias = b1[c];
  float* out = roi_ds + (size_t)r * EMB_K + c * 25;
#pragma unroll
  for (int p = 0; p < 25; ++p) out[p] = acc[p] + bias;
}

// ---------------- K2: emb partial GEMM, k-split 8 ----------------------------
__global__ __launch_bounds__(256) void k_emb_part(const float* __restrict__ roi_ds,
                                                  const float* __restrict__ wembT,
                                                  float* __restrict__ emb_part) { // [8][BN][256]
  const int r0 = blockIdx.x * 16;
  const int kz = blockIdx.y;
  const int c = threadIdx.x;
  const int k0 = kz * (EMB_K / 8);
  float acc[16];
#pragma unroll
  for (int r = 0; r < 16; ++r) acc[r] = 0.f;
#pragma unroll 4
  for (int k = k0; k < k0 + EMB_K / 8; ++k) {
    const float w = wembT[(size_t)k * NFC + c];
#pragma unroll
    for (int r = 0; r < 16; ++r)
      acc[r] = fmaf(w, roi_ds[(size_t)(r0 + r) * EMB_K + k], acc[r]);
  }
#pragma unroll
  for (int r = 0; r < 16; ++r)
    emb_part[((size_t)kz * BN + r0 + r) * NFC + c] = acc[r];
}

__global__ __launch_bounds__(256) void k_emb_reduce(const float* __restrict__ emb_part,
                                                    const float* __restrict__ bemb,
                                                    float* __restrict__ emb) {
  int i = blockIdx.x * 256 + threadIdx.x;
  float s = bemb[i & 255];
#pragma unroll
  for (int z = 0; z < 8; ++z) s += emb_part[(size_t)z * BN * NFC + i];
  emb[i] = s;
}

// ---------------- K3: e2T = (emb @ w_ds2) transposed to [64][768][12] --------
__global__ __launch_bounds__(256) void k_e2(const float* __restrict__ emb,
                                            const float* __restrict__ w_ds2, // [256][768]
                                            float* __restrict__ e2T) {       // [64][768][12]
  const int bn0 = blockIdx.x * 2;            // bn0 even -> both rows same b
  const int b = bn0 / NN;
  const int n0 = bn0 - b * NN;
  const int t = threadIdx.x;
  float a00 = 0, a01 = 0, a02 = 0, a10 = 0, a11 = 0, a12 = 0;
#pragma unroll 4
  for (int o = 0; o < NFC; ++o) {
    const float w0 = w_ds2[(size_t)o * IMG_C + t];
    const float w1 = w_ds2[(size_t)o * IMG_C + t + 256];
    const float w2 = w_ds2[(size_t)o * IMG_C + t + 512];
    const float e0 = emb[(size_t)bn0 * NFC + o];
    const float e1 = emb[(size_t)(bn0 + 1) * NFC + o];
    a00 = fmaf(e0, w0, a00); a01 = fmaf(e0, w1, a01); a02 = fmaf(e0, w2, a02);
    a10 = fmaf(e1, w0, a10); a11 = fmaf(e1, w1, a11); a12 = fmaf(e1, w2, a12);
  }
  float* __restrict__ dst = e2T + (size_t)b * IMG_C * NN;
  dst[(size_t)t * NN + n0]              = a00;
  dst[(size_t)(t + 256) * NN + n0]      = a01;
  dst[(size_t)(t + 512) * NN + n0]      = a02;
  dst[(size_t)t * NN + n0 + 1]          = a10;
  dst[(size_t)(t + 256) * NN + n0 + 1]  = a11;
  dst[(size_t)(t + 512) * NN + n0 + 1]  = a12;
}

// ---------------- K4: flash attention, F -> HBM exactly once -----------------
// Grid (8, 64), 768 threads (12 waves), 2 blocks/CU.  Per 16-column stripe:
//  A: wave w owns c in [64w,64w+64); lane=(cq,s) -> each wave-load covers 4
//     DIFFERENT c rows x 16 consecutive s = 4 fully-used 64B lines (100% line
//     utilization; round-4's (nq,s) layout wasted 3/4 of every request).
//     Each lane computes all 12 n-FMAs; e2 float4 loads are 16-lane-uniform.
//     Lane also copies its F word to LDS. F touches HBM exactly once.
//  in-wave cq-reduce (shfl) -> cross-wave reduce -> online softmax (192 thr)
//  B: thread=c; F row from LDS (4x b128, FPAD=20 proven conflict-free),
//     E broadcast, 192 FMA into persistent acc[12].
__global__ __launch_bounds__(768, 6) void k_attn_flash(
    const float* __restrict__ F,      // [64][768][3600]
    const float* __restrict__ e2T,    // [64][768][12]
    float* __restrict__ part,         // [NCH][64][12][768]
    float* __restrict__ pm,           // [64][NCH][12]
    float* __restrict__ ps) {         // [64][NCH][12]
  __shared__ __align__(16) float F_lds[IMG_C * FPAD];   // 61.4 KB
  __shared__ float a_part[12 * NN * SW];                // 9.2 KB
  __shared__ __align__(16) float E_lds[NN * SW];        // 768 B
  __shared__ float m_l[NN], Z_l[NN], r_l[NN];
  const int b = blockIdx.y;
  const int ch = blockIdx.x;
  const int t = threadIdx.x;
  const int w = t >> 6, lane = t & 63;
  const int cq = lane >> 4, s = lane & 15;
  const int c0 = w * 64;
  const float* __restrict__ Fb = F + (size_t)b * IMG_C * S_TOT;
  const float* __restrict__ e2b = e2T + (size_t)b * IMG_C * NN;

  if (t < NN) { m_l[t] = -3.0e38f; Z_l[t] = 0.f; }
  float acc[NN];
#pragma unroll
  for (int n = 0; n < NN; ++n) acc[n] = 0.f;
  __syncthreads();

  const int nsub = (ch == NCH - 1) ? 29 : 28;
#pragma unroll 1
  for (int sub = 0; sub < nsub; ++sub) {
    const int s0 = ch * 448 + sub * SW;
    // ---- phase A: lane = (cq, s); c = c0 + 4k + cq over k = 0..15 ----
    float a0, a1, a2, a3, a4, a5, a6, a7, a8, a9, a10, a11;
    a0 = a1 = a2 = a3 = a4 = a5 = a6 = a7 = a8 = a9 = a10 = a11 = 0.f;
    {
      const float* __restrict__ Fp = Fb + (size_t)(c0 + cq) * S_TOT + s0 + s;
      const float* __restrict__ ep = e2b + (c0 + cq) * NN;
      float* __restrict__ Fw = &F_lds[(c0 + cq) * FPAD + s];
#pragma unroll 4
      for (int k = 0; k < 16; ++k) {
        const float f = Fp[(size_t)(4 * k) * S_TOT];
        const float4 ea = *reinterpret_cast<const float4*>(ep + 48 * k);
        const float4 eb = *reinterpret_cast<const float4*>(ep + 48 * k + 4);
        const float4 ec = *reinterpret_cast<const float4*>(ep + 48 * k + 8);
        a0  = fmaf(ea.x, f, a0);
        a1  = fmaf(ea.y, f, a1);
        a2  = fmaf(ea.z, f, a2);
        a3  = fmaf(ea.w, f, a3);
        a4  = fmaf(eb.x, f, a4);
        a5  = fmaf(eb.y, f, a5);
        a6  = fmaf(eb.z, f, a6);
        a7  = fmaf(eb.w, f, a7);
        a8  = fmaf(ec.x, f, a8);
        a9  = fmaf(ec.y, f, a9);
        a10 = fmaf(ec.z, f, a10);
        a11 = fmaf(ec.w, f, a11);
        Fw[4 * k * FPAD] = f;
      }
    }
    // ---- in-wave cq-reduce: lanes 0..15 hold sum over 4 cq groups ----
    {
      float av[NN] = {a0, a1, a2, a3, a4, a5, a6, a7, a8, a9, a10, a11};
#pragma unroll
      for (int n = 0; n < NN; ++n) {
        float v = av[n];
        v += __shfl_down(v, 32, 64);
        v += __shfl_down(v, 16, 64);
        if (lane < 16) a_part[(w * NN + n) * SW + lane] = v;
      }
    }
    __syncthreads();
    // ---- reduce 12 wave-partials + online softmax (threads 0..191) ----
    if (t < NN * SW) {
      const int n = t >> 4, si = t & 15;
      float v = 0.f;
#pragma unroll
      for (int ww = 0; ww < 12; ++ww) v += a_part[ww * NN * SW + t];
      float mt = v;
#pragma unroll
      for (int off = 1; off < 16; off <<= 1) mt = fmaxf(mt, __shfl_xor(mt, off, 64));
      const float mo = m_l[n];
      const float mn = fmaxf(mo, mt);
      const float rr = expf(mo - mn);          // 0 on first stripe
      const float ev = expf(v - mn);
      E_lds[n * SW + si] = ev;
      float zs = ev;
#pragma unroll
      for (int off = 1; off < 16; off <<= 1) zs += __shfl_xor(zs, off, 64);
      if (si == 0) { m_l[n] = mn; r_l[n] = rr; Z_l[n] = Z_l[n] * rr + zs; }
    }
    __syncthreads();
    // ---- phase B: thread = c, F row from LDS ----
    {
#pragma unroll
      for (int n = 0; n < NN; ++n) acc[n] *= r_l[n];
      const float* __restrict__ Fr = &F_lds[t * FPAD];
      const float4 f0 = *reinterpret_cast<const float4*>(Fr + 0);
      const float4 f1 = *reinterpret_cast<const float4*>(Fr + 4);
      const float4 f2 = *reinterpret_cast<const float4*>(Fr + 8);
      const float4 f3 = *reinterpret_cast<const float4*>(Fr + 12);
#pragma unroll
      for (int n = 0; n < NN; ++n) {
        const float4 e0 = *reinterpret_cast<const float4*>(&E_lds[n * SW + 0]);
        const float4 e1 = *reinterpret_cast<const float4*>(&E_lds[n * SW + 4]);
        const float4 e2q = *reinterpret_cast<const float4*>(&E_lds[n * SW + 8]);
        const float4 e3 = *reinterpret_cast<const float4*>(&E_lds[n * SW + 12]);
        float d = fmaf(e0.x, f0.x, fmaf(e0.y, f0.y, fmaf(e0.z, f0.z, e0.w * f0.w)));
        d = fmaf(e1.x, f1.x, fmaf(e1.y, f1.y, fmaf(e1.z, f1.z, fmaf(e1.w, f1.w, d))));
        d = fmaf(e2q.x, f2.x, fmaf(e2q.y, f2.y, fmaf(e2q.z, f2.z, fmaf(e2q.w, f2.w, d))));
        d = fmaf(e3.x, f3.x, fmaf(e3.y, f3.y, fmaf(e3.z, f3.z, fmaf(e3.w, f3.w, d))));
        acc[n] += d;
      }
    }
    __syncthreads();   // protect F_lds/a_part/E_lds for next stripe
  }

  // ---- writeout ----
  {
    float* __restrict__ dst = part + (((size_t)ch * BTB + b) * NN) * IMG_C + t;
#pragma unroll
    for (int n = 0; n < NN; ++n) dst[(size_t)n * IMG_C] = acc[n];
  }
  if (t < NN) {
    pm[((size_t)b * NCH + ch) * NN + t] = m_l[t];
    ps[((size_t)b * NCH + ch) * NN + t] = Z_l[t];
  }
}

// ---------------- K5: combine chunk partials -> ctx768 -----------------------
__global__ __launch_bounds__(256) void k_combine(
    const float* __restrict__ part, const float* __restrict__ pm,
    const float* __restrict__ ps, float* __restrict__ ctx768) {  // [BN][768]
  const int bn = blockIdx.x;            // b*12+n
  const int b = bn / NN, n = bn - b * NN;
  const int t = threadIdx.x;
  float mv[NCH];
  float m = -3.0e38f;
#pragma unroll
  for (int ch = 0; ch < NCH; ++ch) {
    mv[ch] = pm[((size_t)b * NCH + ch) * NN + n];
    m = fmaxf(m, mv[ch]);
  }
  float Z = 0.f, al[NCH];
#pragma unroll
  for (int ch = 0; ch < NCH; ++ch) {
    al[ch] = expf(mv[ch] - m);
    Z += ps[((size_t)b * NCH + ch) * NN + n] * al[ch];
  }
  const float rz = 1.0f / Z;
#pragma unroll 1
  for (int ci = 0; ci < 3; ++ci) {
    const int c = ci * 256 + t;
    float s = 0.f;
#pragma unroll
    for (int ch = 0; ch < NCH; ++ch)
      s += part[(((size_t)ch * BTB + b) * NN + n) * IMG_C + c] * al[ch];
    ctx768[(size_t)bn * IMG_C + c] = s * rz;
  }
}

// ---------------- K6: ctx = W_ds2 . ctx768 + b_ds2, +emb residual, LN1 -------
__global__ __launch_bounds__(256) void k_ctx_ln1(
    const float* __restrict__ ctx768, const float* __restrict__ wds2T, // [768][256]
    const float* __restrict__ b_ds2, const float* __restrict__ emb,
    const float* __restrict__ g, const float* __restrict__ be,
    float* __restrict__ x) {
  __shared__ float sm[4];
  const int r0 = blockIdx.x * 3;
  const int o = threadIdx.x;
  float acc[3] = {0.f, 0.f, 0.f};
#pragma unroll 2
  for (int cc = 0; cc < IMG_C; ++cc) {
    const float w = wds2T[(size_t)cc * NFC + o];
#pragma unroll
    for (int r = 0; r < 3; ++r)
      acc[r] = fmaf(w, ctx768[(size_t)(r0 + r) * IMG_C + cc], acc[r]);
  }
  const float bv = b_ds2[o], gv = g[o], bev = be[o];
#pragma unroll 1
  for (int r = 0; r < 3; ++r) {
    const float val = acc[r] + bv + emb[(size_t)(r0 + r) * NFC + o];
    const float mu = blockSum256(val, sm) * (1.0f / NFC);
    const float d = val - mu;
    const float var = blockSum256(d * d, sm) * (1.0f / NFC);
    x[(size_t)(r0 + r) * NFC + o] = d * rsqrtf(var + LN_EPS) * gv + bev;
  }
}

// ---------------- K7: FFN + residual + LN2 -----------------------------------
__global__ __launch_bounds__(256) void k_ffn_ln2(const float* __restrict__ x,
                                                 const float* __restrict__ w1T,
                                                 const float* __restrict__ b1,
                                                 const float* __restrict__ w2T,
                                                 const float* __restrict__ b2,
                                                 const float* __restrict__ g2,
                                                 const float* __restrict__ be2,
                                                 float* __restrict__ out) {
  __shared__ float hs[3][NFC];
  __shared__ float sm[4];
  const int r0 = blockIdx.x * 3;
  const int o = threadIdx.x;
  float acc[3] = {0.f, 0.f, 0.f};
#pragma unroll 4
  for (int c = 0; c < NFC; ++c) {
    const float w = w1T[(size_t)c * NFC + o];
#pragma unroll
    for (int r = 0; r < 3; ++r)
      acc[r] = fmaf(w, x[(size_t)(r0 + r) * NFC + c], acc[r]);
  }
  const float bb = b1[o];
#pragma unroll
  for (int r = 0; r < 3; ++r) hs[r][o] = fmaxf(acc[r] + bb, 0.0f);
  __syncthreads();
  float acc2[3] = {0.f, 0.f, 0.f};
#pragma unroll 4
  for (int c = 0; c < NFC; ++c) {
    const float w = w2T[(size_t)c * NFC + o];
#pragma unroll
    for (int r = 0; r < 3; ++r) acc2[r] = fmaf(w, hs[r][c], acc2[r]);
  }
  const float b2v = b2[o], gv = g2[o], bev = be2[o];
#pragma unroll 1
  for (int r = 0; r < 3; ++r) {
    const float val = acc2[r] + b2v + x[(size_t)(r0 + r) * NFC + o];
    const float mu = blockSum256(val, sm) * (1.0f / NFC);
    const float d = val - mu;
    const float var = blockSum256(d * d, sm) * (1.0f / NFC);
    out[(size_t)(r0 + r) * NFC + o] = d * rsqrtf(var + LN_EPS) * gv + bev;
  }
}

// ---------------- launch -----------------------------------------------------
extern "C" void kernel_launch(void* const* d_in, const int* in_sizes, int n_in,
                              void* d_out, int out_size, void* d_ws, size_t ws_size,
                              hipStream_t stream) {
  const float* roi_feature   = (const float*)d_in[0];
  const float* image_feature = (const float*)d_in[1];
  const float* w_ds1  = (const float*)d_in[2];
  const float* b_ds1  = (const float*)d_in[3];
  const float* w_ds2  = (const float*)d_in[4];
  const float* b_ds2  = (const float*)d_in[5];
  const float* w_emb  = (const float*)d_in[6];
  const float* b_emb  = (const float*)d_in[7];
  const float* g1     = (const float*)d_in[8];
  const float* be1    = (const float*)d_in[9];
  const float* ffn_w1 = (const float*)d_in[10];
  const float* ffn_b1 = (const float*)d_in[11];
  const float* ffn_w2 = (const float*)d_in[12];
  const float* ffn_b2 = (const float*)d_in[13];
  const float* g2     = (const float*)d_in[14];
  const float* be2    = (const float*)d_in[15];
  float* out = (float*)d_out;

  float* p = (float*)d_ws;
  float* w1T    = p;   p += 1024 * 256;
  float* wembT  = p;   p += 6400 * 256;
  float* wds2T  = p;   p += 768 * 256;
  float* w1Tf   = p;   p += 256 * 256;
  float* w2Tf   = p;   p += 256 * 256;
  float* roi_ds = p;   p += 768 * 6400;
  float* emb_part = p; p += 8 * 768 * 256;
  float* emb    = p;   p += 768 * 256;
  float* e2T    = p;   p += 768 * 768;                       // [64][768][12]
  float* part   = p;   p += (size_t)NCH * BTB * NN * IMG_C;  // 4.72M floats
  float* pm     = p;   p += BTB * NCH * NN;
  float* ps     = p;   p += BTB * NCH * NN;
  float* ctx768 = p;   p += 768 * 768;
  float* xb     = p;   p += 768 * 256;

  k_transpose_all<<<544, 256, 0, stream>>>(w_ds1, w_emb, w_ds2, ffn_w1, ffn_w2,
                                           w1T, wembT, wds2T, w1Tf, w2Tf);
  k_ds1<<<BN, 256, 0, stream>>>(roi_feature, w1T, b_ds1, roi_ds);
  k_emb_part<<<dim3(48, 8), 256, 0, stream>>>(roi_ds, wembT, emb_part);
  k_emb_reduce<<<768, 256, 0, stream>>>(emb_part, b_emb, emb);
  k_e2<<<384, 256, 0, stream>>>(emb, w_ds2, e2T);
  k_attn_flash<<<dim3(NCH, BTB), 768, 0, stream>>>(image_feature, e2T, part, pm, ps);
  k_combine<<<768, 256, 0, stream>>>(part, pm, ps, ctx768);
  k_ctx_ln1<<<256, 256, 0, stream>>>(ctx768, wds2T, b_ds2, emb, g1, be1, xb);
  k_ffn_ln2<<<256, 256, 0, stream>>>(xb, w1Tf, ffn_b1, w2Tf, ffn_b2, g2, be2, out);
}